// Round 4
// baseline (396.682 us; speedup 1.0000x reference)
//
#include <hip/hip_runtime.h>
#include <math.h>

#define NPART 32768
#define MS 50
#define BLOCK 256

typedef __attribute__((ext_vector_type(8))) short bfrag;   // 8 bf16 (4 VGPRs)
typedef __attribute__((ext_vector_type(4))) float ffrag;   // 4 fp32 (MFMA C/D)

// float -> bf16 bits, round-to-nearest-even (init-time staging only)
__device__ __forceinline__ unsigned short f2bf(float x) {
    unsigned u = __float_as_uint(x);
    u += 0x7fffu + ((u >> 16) & 1u);
    return (unsigned short)(u >> 16);
}

// Hot-loop pack: single HW instruction (no builtin on gfx950 — learn_hip m240).
__device__ __forceinline__ unsigned pk2(float a, float b) {
    unsigned r;
    asm("v_cvt_pk_bf16_f32 %0, %1, %2" : "=v"(r) : "v"(a), "v"(b));
    return r;
}

// Guaranteed-native transcendentals: v_exp_f32 computes 2^x, v_rcp_f32 = 1/x.
__device__ __forceinline__ float nexp2(float x) {
#if __has_builtin(__builtin_amdgcn_exp2f)
    return __builtin_amdgcn_exp2f(x);
#else
    float r;
    asm("v_exp_f32 %0, %1" : "=v"(r) : "v"(x));
    return r;
#endif
}
__device__ __forceinline__ float nrcp(float x) {
#if __has_builtin(__builtin_amdgcn_rcpf)
    return __builtin_amdgcn_rcpf(x);
#else
    float r;
    asm("v_rcp_f32 %0, %1" : "=v"(r) : "v"(x));
    return r;
#endif
}

// tanh(x) = 1 - 2/(2^(2*log2e*x)+1). 5 VALU ops (mul,exp,add,rcp,fma).
__device__ __forceinline__ float fast_tanh(float x) {
    const float c = 2.8853900817779268f;   // 2*log2(e)
    float e = nexp2(x * c);
    float r = nrcp(e + 1.0f);
    return fmaf(-2.0f, r, 1.0f);
}

// OCCUPANCY SPLIT (R3): 4 waves/block = 2 pairs. Wave w: g = w&1 (particle
// group of 16), hh = w>>1 (hidden half 0/1). Each wave computes hidden units
// [64hh, 64hh+64): GEMM1 = 4 MFMA (mt local 0..3, global 4hh+mt), tanh 16,
// GEMM2 partial over global kt in {2hh, 2hh+1}. Partial Z's combine through
// LDS (f32 add) with __syncthreads(). Grid 1024 -> 4096 waves = 4/SIMD
// (was 2048 = 2/SIMD, latency-bound).
//
// Lane map within a wave (unchanged): p = lane&15 (particle), q = lane>>4
// (dim block; lane owns X dims [8q,8q+8) = MFMA B-layout). GEMM2 layout trick
// unchanged: tanh'd GEMM1 C-regs feed GEMM2 as A-operand with kappa-permuted
// W2 B-frags; local A-frag(ktl) element j = C[2ktl+(j>>2)][j&3] holds global
// kappa = 64hh + 32ktl + 16(j>>2) + 4q + (j&3).
// X/noise/pack duplicated across the pair (noise re-reads hit L1, same CU);
// V and output stores gated to hh==0.
__global__ __launch_bounds__(BLOCK, 4)
void fused_sde_mfma(const float* __restrict__ obs,
                    const float* __restrict__ x0,
                    const float* __restrict__ v0,
                    const float* __restrict__ noise,
                    const float* __restrict__ gW1,
                    const float* __restrict__ gb1,
                    const float* __restrict__ gW2,
                    const float* __restrict__ gb2,
                    const float* __restrict__ gtheta,
                    const int* __restrict__ gobs_idx,
                    const int* __restrict__ gctrl,
                    float* __restrict__ outX,
                    float* __restrict__ outV)
{
    // Zlds[wave][particle][dim], pitch 36 floats (144 B) -> <=2-way aliasing.
    __shared__ __align__(16) float Zlds[4][16][36];

    const int tid  = threadIdx.x;
    const int w    = tid >> 6;
    const int g    = w & 1;        // particle group within block
    const int hh   = w >> 1;       // hidden half
    const int lane = tid & 63;
    const int p    = lane & 15;
    const int q    = lane >> 4;
    const int part = blockIdx.x * 32 + g * 16 + p;

    const float theta = gtheta[0];
    const float tfeat = (float)gobs_idx[0];
    const float cr    = (float)gctrl[0];
    const float dt      = 1.0f / (float)MS;
    const float sqrt_dt = sqrtf(dt);
    const float ax  = 1.0f - dt * theta;
    const float bcr = dt * cr;
    const float kv  = dt * (0.5f - cr);

    // ---- GEMM1 A-fragments: W1 X-block, this wave's hidden half ----
    bfrag A1[4];
    #pragma unroll
    for (int mt = 0; mt < 4; ++mt) {
        const int h = 64 * hh + 16 * mt + p;
        bfrag a;
        #pragma unroll
        for (int j = 0; j < 8; ++j)
            a[j] = (short)f2bf(gW1[(8 * q + j) * 128 + h]);
        A1[mt] = a;
    }

    // ---- GEMM2 B-fragments: W2 rows kappa-permuted, this wave's kt pair ----
    bfrag B2[2][2];
    #pragma unroll
    for (int nt = 0; nt < 2; ++nt) {
        #pragma unroll
        for (int ktl = 0; ktl < 2; ++ktl) {
            const int kt = 2 * hh + ktl;
            bfrag b;
            #pragma unroll
            for (int j = 0; j < 8; ++j) {
                const int h = 32 * kt + 16 * (j >> 2) + 4 * q + (j & 3);  // kappa
                b[j] = (short)f2bf(gW2[h * 32 + 16 * nt + p]);
            }
            B2[nt][ktl] = b;
        }
    }

    // ---- static C-init for GEMM1 (this half): Stat = b1 + Y.W1y + t*W1t ----
    ffrag Stat[4], W1s[4];
    #pragma unroll
    for (int mt = 0; mt < 4; ++mt) {
        #pragma unroll
        for (int r = 0; r < 4; ++r) {
            const int h = 64 * hh + 16 * mt + 4 * q + r;
            float acc = gb1[h];
            #pragma unroll
            for (int j = 0; j < 8; ++j)
                acc = fmaf(obs[j], gW1[(32 + j) * 128 + h], acc);
            acc = fmaf(tfeat, gW1[41 * 128 + h], acc);
            Stat[mt][r] = acc;
            W1s[mt][r]  = gW1[40 * 128 + h];
        }
    }

    // GEMM2 C-init: b2 carried by the hh==0 wave only (partials sum in LDS).
    const float bz0 = (hh == 0) ? gb2[p]      : 0.0f;
    const float bz1 = (hh == 0) ? gb2[16 + p] : 0.0f;
    const ffrag Z0i = ffrag{bz0, bz0, bz0, bz0};
    const ffrag Z1i = ffrag{bz1, bz1, bz1, bz1};

    // ---- per-lane state (duplicated across the pair) ----
    float X[8];
    {
        const float4* xp = (const float4*)(x0 + (size_t)part * 32 + 8 * q);
        float4 a = xp[0], b = xp[1];
        X[0] = a.x; X[1] = a.y; X[2] = a.z; X[3] = a.w;
        X[4] = b.x; X[5] = b.y; X[6] = b.z; X[7] = b.w;
    }
    float V = (hh == 0) ? v0[part] : 0.0f;

    const float* nbase = noise + (size_t)part * 32 + 8 * q;
    float4 nc0 = ((const float4*)nbase)[0];
    float4 nc1 = ((const float4*)nbase)[1];

    float* zbase = &Zlds[w][0][0];
    const float* zrow0 = &Zlds[g][p][0];       // hh=0 partial
    const float* zrow1 = &Zlds[2 + g][p][0];   // hh=1 partial

    #pragma unroll 1
    for (int m = 0; m < MS; ++m) {
        const int mn = (m + 1 < MS) ? m + 1 : m;
        const float* np = nbase + (size_t)mn * ((size_t)NPART * 32);
        float4 nn0 = ((const float4*)np)[0];
        float4 nn1 = ((const float4*)np)[1];

        // B fragment: X -> packed bf16
        int4 bxw = make_int4((int)pk2(X[0], X[1]), (int)pk2(X[2], X[3]),
                             (int)pk2(X[4], X[5]), (int)pk2(X[6], X[7]));
        bfrag BX = __builtin_bit_cast(bfrag, bxw);

        const float s = (float)m * dt;

        // ---- GEMM1: 4 independent MFMAs on this wave's hidden half ----
        ffrag C[4];
        #pragma unroll
        for (int mt = 0; mt < 4; ++mt) {
            ffrag c;
            #pragma unroll
            for (int r = 0; r < 4; ++r) c[r] = fmaf(s, W1s[mt][r], Stat[mt][r]);
            C[mt] = c;
        }
        #pragma unroll
        for (int mt = 0; mt < 4; ++mt)
            C[mt] = __builtin_amdgcn_mfma_f32_16x16x32_bf16(A1[mt], BX, C[mt], 0, 0, 0);

        // ---- tanh + pack: C-regs become GEMM2 A-fragments directly ----
        uint2 Hpk[4];
        #pragma unroll
        for (int mt = 0; mt < 4; ++mt) {
            const unsigned u0 = pk2(fast_tanh(C[mt][0]), fast_tanh(C[mt][1]));
            const unsigned u1 = pk2(fast_tanh(C[mt][2]), fast_tanh(C[mt][3]));
            Hpk[mt] = make_uint2(u0, u1);
        }

        // ---- GEMM2 partial: this wave's kt pair, 2-deep chains ----
        ffrag D0 = Z0i, D1 = Z1i;
        #pragma unroll
        for (int ktl = 0; ktl < 2; ++ktl) {
            int4 aw = make_int4((int)Hpk[2 * ktl].x, (int)Hpk[2 * ktl].y,
                                (int)Hpk[2 * ktl + 1].x, (int)Hpk[2 * ktl + 1].y);
            bfrag A = __builtin_bit_cast(bfrag, aw);
            D0 = __builtin_amdgcn_mfma_f32_16x16x32_bf16(A, B2[0][ktl], D0, 0, 0, 0);
            D1 = __builtin_amdgcn_mfma_f32_16x16x32_bf16(A, B2[1][ktl], D1, 0, 0, 0);
        }
        // D0: Zpart[particle 4q+r][outdim p], D1: outdim 16+p

        // ---- scatter partials to [particle][dim] ----
        #pragma unroll
        for (int r = 0; r < 4; ++r) {
            float* zr = zbase + (4 * q + r) * 36;
            zr[p]      = D0[r];
            zr[16 + p] = D1[r];
        }

        __syncthreads();   // partials visible across the pair

        float4 a0 = *(const float4*)&zrow0[8 * q];
        float4 a1 = *(const float4*)&zrow0[8 * q + 4];
        float4 b0 = *(const float4*)&zrow1[8 * q];
        float4 b1 = *(const float4*)&zrow1[8 * q + 4];
        float Z[8] = {a0.x + b0.x, a0.y + b0.y, a0.z + b0.z, a0.w + b0.w,
                      a1.x + b1.x, a1.y + b1.y, a1.z + b1.z, a1.w + b1.w};
        float Nn[8] = {nc0.x, nc0.y, nc0.z, nc0.w, nc1.x, nc1.y, nc1.z, nc1.w};

        // V: (0.5-cr)*dt*sum(Z^2) + sqrt_dt*sum(Z*n)  (hh==0 wave only)
        if (hh == 0) {
            float s2 = 0.0f, sn = 0.0f;
            #pragma unroll
            for (int j = 0; j < 8; ++j) {
                s2 = fmaf(Z[j], Z[j], s2);
                sn = fmaf(Z[j], Nn[j], sn);
            }
            s2 += __shfl_xor(s2, 16); s2 += __shfl_xor(s2, 32);
            sn += __shfl_xor(sn, 16); sn += __shfl_xor(sn, 32);
            V = fmaf(kv, s2, fmaf(sqrt_dt, sn, V));
        }

        // X = ax*X - bcr*Z + sqrt_dt*n   (both waves keep identical X state)
        #pragma unroll
        for (int j = 0; j < 8; ++j) {
            float t = fmaf(-bcr, Z[j], sqrt_dt * Nn[j]);
            X[j] = fmaf(ax, X[j], t);
        }

        nc0 = nn0; nc1 = nn1;

        __syncthreads();   // protect Zlds WAR before next scatter
    }

    if (hh == 0) {
        float4* xout = (float4*)(outX + (size_t)part * 32 + 8 * q);
        xout[0] = make_float4(X[0], X[1], X[2], X[3]);
        xout[1] = make_float4(X[4], X[5], X[6], X[7]);
        if (q == 0) outV[part] = V;
    }
}

extern "C" void kernel_launch(void* const* d_in, const int* in_sizes, int n_in,
                              void* d_out, int out_size, void* d_ws, size_t ws_size,
                              hipStream_t stream) {
    const float* obs   = (const float*)d_in[0];
    const float* x0    = (const float*)d_in[1];
    const float* v0    = (const float*)d_in[2];
    const float* noise = (const float*)d_in[3];
    const float* W1    = (const float*)d_in[4];
    const float* b1    = (const float*)d_in[5];
    const float* W2    = (const float*)d_in[6];
    const float* b2    = (const float*)d_in[7];
    const float* th    = (const float*)d_in[8];
    const int*   oi    = (const int*)d_in[9];
    const int*   cr    = (const int*)d_in[10];

    float* outX = (float*)d_out;
    float* outV = outX + (size_t)NPART * 32;

    dim3 grid(NPART / 32);   // 1024 blocks x 4 waves; wave pair splits hidden
    fused_sde_mfma<<<grid, BLOCK, 0, stream>>>(obs, x0, v0, noise, W1, b1, W2, b2,
                                               th, oi, cr, outX, outV);
}

// Round 6
// 382.002 us; speedup vs baseline: 1.0384x; 1.0384x over previous
//
#include <hip/hip_runtime.h>
#include <math.h>

#define NPART 32768
#define MS 50
#define BLOCK 256

typedef __attribute__((ext_vector_type(8))) short bfrag;   // 8 bf16 (4 VGPRs)
typedef __attribute__((ext_vector_type(4))) float ffrag;   // 4 fp32 (MFMA C/D)

// float -> bf16 bits, round-to-nearest-even (init-time staging only)
__device__ __forceinline__ unsigned short f2bf(float x) {
    unsigned u = __float_as_uint(x);
    u += 0x7fffu + ((u >> 16) & 1u);
    return (unsigned short)(u >> 16);
}

// Hot-loop pack: single HW instruction (no builtin on gfx950 — learn_hip m240).
__device__ __forceinline__ unsigned pk2(float a, float b) {
    unsigned r;
    asm("v_cvt_pk_bf16_f32 %0, %1, %2" : "=v"(r) : "v"(a), "v"(b));
    return r;
}

// Guaranteed-native transcendentals: v_exp_f32 computes 2^x, v_rcp_f32 = 1/x.
__device__ __forceinline__ float nexp2(float x) {
#if __has_builtin(__builtin_amdgcn_exp2f)
    return __builtin_amdgcn_exp2f(x);
#else
    float r;
    asm("v_exp_f32 %0, %1" : "=v"(r) : "v"(x));
    return r;
#endif
}
__device__ __forceinline__ float nrcp(float x) {
#if __has_builtin(__builtin_amdgcn_rcpf)
    return __builtin_amdgcn_rcpf(x);
#else
    float r;
    asm("v_rcp_f32 %0, %1" : "=v"(r) : "v"(x));
    return r;
#endif
}

// tanh(x) = 1 - 2/(2^(2*log2e*x)+1). 5 VALU ops (mul,exp,add,rcp,fma).
__device__ __forceinline__ float fast_tanh(float x) {
    const float c = 2.8853900817779268f;   // 2*log2(e)
    float e = nexp2(x * c);
    float r = nrcp(e + 1.0f);
    return fmaf(-2.0f, r, 1.0f);
}

// OCCUPANCY SPLIT, fixed (R5): 4 waves/block = 2 pairs. Wave w = 2*hh + g:
// g = w&1 (particle group of 16), hh = w>>1 (hidden half). Each wave computes
// hidden units [64hh, 64hh+64): GEMM1 = 4 MFMA, tanh 16, GEMM2 partial over
// global kt in {2hh, 2hh+1}. Partial Z's combine through LDS.
//
// R4 regression causes, fixed here:
//  - spills (VGPR squeezed to 64 by launch_bounds(...,4), 147 MB scratch):
//    launch_bounds(256,3) caps at ~168 regs; actual ~110 -> no spill, and
//    110 <= 128 still admits 4 waves/SIMD.
//  - duplicated noise fetch (176 MB): only hh==0 waves keep X/V/noise and do
//    the update; hh==1 waves receive packed-bf16 X (int4/lane) via BXlds.
//
// Lane map within a wave (unchanged): p = lane&15 (particle), q = lane>>4
// (lane owns X dims [8q,8q+8) = MFMA B-layout). GEMM2 layout trick unchanged:
// tanh'd GEMM1 C-regs feed GEMM2 as A-operand with kappa-permuted W2 B-frags;
// local A-frag(ktl) elem j holds kappa = 64hh + 32ktl + 16(j>>2) + 4q + (j&3).
__global__ __launch_bounds__(BLOCK, 3)
void fused_sde_mfma(const float* __restrict__ obs,
                    const float* __restrict__ x0,
                    const float* __restrict__ v0,
                    const float* __restrict__ noise,
                    const float* __restrict__ gW1,
                    const float* __restrict__ gb1,
                    const float* __restrict__ gW2,
                    const float* __restrict__ gb2,
                    const float* __restrict__ gtheta,
                    const int* __restrict__ gobs_idx,
                    const int* __restrict__ gctrl,
                    float* __restrict__ outX,
                    float* __restrict__ outV)
{
    // Zlds[wave][particle][dim], pitch 36 floats (144 B) -> <=2-way aliasing.
    __shared__ __align__(16) float Zlds[4][16][36];
    __shared__ __align__(16) int4 BXlds[2][64];   // packed-bf16 X broadcast

    const int tid  = threadIdx.x;
    const int w    = tid >> 6;
    const int g    = w & 1;        // particle group within block
    const int hh   = w >> 1;       // hidden half
    const int lane = tid & 63;
    const int p    = lane & 15;
    const int q    = lane >> 4;
    const int part = blockIdx.x * 32 + g * 16 + p;

    const float theta = gtheta[0];
    const float tfeat = (float)gobs_idx[0];
    const float cr    = (float)gctrl[0];
    const float dt      = 1.0f / (float)MS;
    const float sqrt_dt = sqrtf(dt);
    const float ax  = 1.0f - dt * theta;
    const float bcr = dt * cr;
    const float kv  = dt * (0.5f - cr);

    // ---- GEMM1 A-fragments: W1 X-block, this wave's hidden half ----
    bfrag A1[4];
    #pragma unroll
    for (int mt = 0; mt < 4; ++mt) {
        const int h = 64 * hh + 16 * mt + p;
        bfrag a;
        #pragma unroll
        for (int j = 0; j < 8; ++j)
            a[j] = (short)f2bf(gW1[(8 * q + j) * 128 + h]);
        A1[mt] = a;
    }

    // ---- GEMM2 B-fragments: W2 rows kappa-permuted, this wave's kt pair ----
    bfrag B2[2][2];
    #pragma unroll
    for (int nt = 0; nt < 2; ++nt) {
        #pragma unroll
        for (int ktl = 0; ktl < 2; ++ktl) {
            const int kt = 2 * hh + ktl;
            bfrag b;
            #pragma unroll
            for (int j = 0; j < 8; ++j) {
                const int h = 32 * kt + 16 * (j >> 2) + 4 * q + (j & 3);  // kappa
                b[j] = (short)f2bf(gW2[h * 32 + 16 * nt + p]);
            }
            B2[nt][ktl] = b;
        }
    }

    // ---- static C-init for GEMM1 (this half): Stat = b1 + Y.W1y + t*W1t ----
    ffrag Stat[4], W1s[4];
    #pragma unroll
    for (int mt = 0; mt < 4; ++mt) {
        #pragma unroll
        for (int r = 0; r < 4; ++r) {
            const int h = 64 * hh + 16 * mt + 4 * q + r;
            float acc = gb1[h];
            #pragma unroll
            for (int j = 0; j < 8; ++j)
                acc = fmaf(obs[j], gW1[(32 + j) * 128 + h], acc);
            acc = fmaf(tfeat, gW1[41 * 128 + h], acc);
            Stat[mt][r] = acc;
            W1s[mt][r]  = gW1[40 * 128 + h];
        }
    }

    // GEMM2 C-init: b2 carried by the hh==0 wave only (partials sum in LDS).
    const float bz0 = (hh == 0) ? gb2[p]      : 0.0f;
    const float bz1 = (hh == 0) ? gb2[16 + p] : 0.0f;
    const ffrag Z0i = ffrag{bz0, bz0, bz0, bz0};
    const ffrag Z1i = ffrag{bz1, bz1, bz1, bz1};

    // ---- per-lane state: ONLY hh==0 waves keep X/V/noise ----
    float X[8];
    float V = 0.0f;
    float4 nc0, nc1;
    int4 bxreg;
    const float* nbase = noise + (size_t)part * 32 + 8 * q;
    if (hh == 0) {
        const float4* xp = (const float4*)(x0 + (size_t)part * 32 + 8 * q);
        float4 a = xp[0], b = xp[1];
        X[0] = a.x; X[1] = a.y; X[2] = a.z; X[3] = a.w;
        X[4] = b.x; X[5] = b.y; X[6] = b.z; X[7] = b.w;
        V = v0[part];
        nc0 = ((const float4*)nbase)[0];
        nc1 = ((const float4*)nbase)[1];
        bxreg = make_int4((int)pk2(X[0], X[1]), (int)pk2(X[2], X[3]),
                          (int)pk2(X[4], X[5]), (int)pk2(X[6], X[7]));
        BXlds[g][lane] = bxreg;
    }
    __syncthreads();

    float* zbase = &Zlds[w][0][0];
    const float* zrow0 = &Zlds[g][p][0];       // hh=0 partial
    const float* zrow1 = &Zlds[2 + g][p][0];   // hh=1 partial

    #pragma unroll 1
    for (int m = 0; m < MS; ++m) {
        // noise prefetch for NEXT step (hh==0 only) — hides under GEMM phase
        float4 nn0, nn1;
        if (hh == 0) {
            const int mn = (m + 1 < MS) ? m + 1 : m;
            const float* np = nbase + (size_t)mn * ((size_t)NPART * 32);
            nn0 = ((const float4*)np)[0];
            nn1 = ((const float4*)np)[1];
        }

        // B fragment: packed bf16 X (reg copy on hh=0; LDS broadcast on hh=1)
        int4 bxw;
        if (hh == 0) bxw = bxreg;
        else         bxw = BXlds[g][lane];
        bfrag BX = __builtin_bit_cast(bfrag, bxw);

        const float s = (float)m * dt;

        // ---- GEMM1: 4 independent MFMAs on this wave's hidden half ----
        ffrag C[4];
        #pragma unroll
        for (int mt = 0; mt < 4; ++mt) {
            ffrag c;
            #pragma unroll
            for (int r = 0; r < 4; ++r) c[r] = fmaf(s, W1s[mt][r], Stat[mt][r]);
            C[mt] = c;
        }
        #pragma unroll
        for (int mt = 0; mt < 4; ++mt)
            C[mt] = __builtin_amdgcn_mfma_f32_16x16x32_bf16(A1[mt], BX, C[mt], 0, 0, 0);

        // ---- tanh + pack: C-regs become GEMM2 A-fragments directly ----
        uint2 Hpk[4];
        #pragma unroll
        for (int mt = 0; mt < 4; ++mt) {
            const unsigned u0 = pk2(fast_tanh(C[mt][0]), fast_tanh(C[mt][1]));
            const unsigned u1 = pk2(fast_tanh(C[mt][2]), fast_tanh(C[mt][3]));
            Hpk[mt] = make_uint2(u0, u1);
        }

        // ---- GEMM2 partial: this wave's kt pair ----
        ffrag D0 = Z0i, D1 = Z1i;
        #pragma unroll
        for (int ktl = 0; ktl < 2; ++ktl) {
            int4 aw = make_int4((int)Hpk[2 * ktl].x, (int)Hpk[2 * ktl].y,
                                (int)Hpk[2 * ktl + 1].x, (int)Hpk[2 * ktl + 1].y);
            bfrag A = __builtin_bit_cast(bfrag, aw);
            D0 = __builtin_amdgcn_mfma_f32_16x16x32_bf16(A, B2[0][ktl], D0, 0, 0, 0);
            D1 = __builtin_amdgcn_mfma_f32_16x16x32_bf16(A, B2[1][ktl], D1, 0, 0, 0);
        }

        // ---- scatter partials to [particle][dim] ----
        #pragma unroll
        for (int r = 0; r < 4; ++r) {
            float* zr = zbase + (4 * q + r) * 36;
            zr[p]      = D0[r];
            zr[16 + p] = D1[r];
        }

        __syncthreads();   // sync1: partials visible; BXlds free for overwrite

        if (hh == 0) {
            float4 a0 = *(const float4*)&zrow0[8 * q];
            float4 a1 = *(const float4*)&zrow0[8 * q + 4];
            float4 b0 = *(const float4*)&zrow1[8 * q];
            float4 b1 = *(const float4*)&zrow1[8 * q + 4];
            float Z[8] = {a0.x + b0.x, a0.y + b0.y, a0.z + b0.z, a0.w + b0.w,
                          a1.x + b1.x, a1.y + b1.y, a1.z + b1.z, a1.w + b1.w};
            float Nn[8] = {nc0.x, nc0.y, nc0.z, nc0.w, nc1.x, nc1.y, nc1.z, nc1.w};

            // V: (0.5-cr)*dt*sum(Z^2) + sqrt_dt*sum(Z*n)
            float s2 = 0.0f, sn = 0.0f;
            #pragma unroll
            for (int j = 0; j < 8; ++j) {
                s2 = fmaf(Z[j], Z[j], s2);
                sn = fmaf(Z[j], Nn[j], sn);
            }
            s2 += __shfl_xor(s2, 16); s2 += __shfl_xor(s2, 32);
            sn += __shfl_xor(sn, 16); sn += __shfl_xor(sn, 32);
            V = fmaf(kv, s2, fmaf(sqrt_dt, sn, V));

            // X = ax*X - bcr*Z + sqrt_dt*n
            #pragma unroll
            for (int j = 0; j < 8; ++j) {
                float t = fmaf(-bcr, Z[j], sqrt_dt * Nn[j]);
                X[j] = fmaf(ax, X[j], t);
            }

            nc0 = nn0; nc1 = nn1;

            bxreg = make_int4((int)pk2(X[0], X[1]), (int)pk2(X[2], X[3]),
                              (int)pk2(X[4], X[5]), (int)pk2(X[6], X[7]));
            BXlds[g][lane] = bxreg;
        }

        __syncthreads();   // sync2: new BX visible; Zlds free (WAR)
    }

    if (hh == 0) {
        float4* xout = (float4*)(outX + (size_t)part * 32 + 8 * q);
        xout[0] = make_float4(X[0], X[1], X[2], X[3]);
        xout[1] = make_float4(X[4], X[5], X[6], X[7]);
        if (q == 0) outV[part] = V;
    }
}

extern "C" void kernel_launch(void* const* d_in, const int* in_sizes, int n_in,
                              void* d_out, int out_size, void* d_ws, size_t ws_size,
                              hipStream_t stream) {
    const float* obs   = (const float*)d_in[0];
    const float* x0    = (const float*)d_in[1];
    const float* v0    = (const float*)d_in[2];
    const float* noise = (const float*)d_in[3];
    const float* W1    = (const float*)d_in[4];
    const float* b1    = (const float*)d_in[5];
    const float* W2    = (const float*)d_in[6];
    const float* b2    = (const float*)d_in[7];
    const float* th    = (const float*)d_in[8];
    const int*   oi    = (const int*)d_in[9];
    const int*   cr    = (const int*)d_in[10];

    float* outX = (float*)d_out;
    float* outV = outX + (size_t)NPART * 32;

    dim3 grid(NPART / 32);   // 1024 blocks x 4 waves; wave pair splits hidden
    fused_sde_mfma<<<grid, BLOCK, 0, stream>>>(obs, x0, v0, noise, W1, b1, W2, b2,
                                               th, oi, cr, outX, outV);
}

// Round 10
// 323.510 us; speedup vs baseline: 1.2262x; 1.1808x over previous
//
#include <hip/hip_runtime.h>
#include <math.h>

#define NPART 32768
#define MS 50
#define BLOCK 256

typedef __attribute__((ext_vector_type(8))) short bfrag;   // 8 bf16 (4 VGPRs)
typedef __attribute__((ext_vector_type(4))) float ffrag;   // 4 fp32 (MFMA C/D)

// float -> bf16 bits, round-to-nearest-even (init-time staging only)
__device__ __forceinline__ unsigned short f2bf(float x) {
    unsigned u = __float_as_uint(x);
    u += 0x7fffu + ((u >> 16) & 1u);
    return (unsigned short)(u >> 16);
}

// Hot-loop pack: single HW instruction (no builtin on gfx950 — learn_hip m240).
__device__ __forceinline__ unsigned pk2(float a, float b) {
    unsigned r;
    asm("v_cvt_pk_bf16_f32 %0, %1, %2" : "=v"(r) : "v"(a), "v"(b));
    return r;
}

// Guaranteed-native transcendentals: v_exp_f32 computes 2^x, v_rcp_f32 = 1/x.
__device__ __forceinline__ float nexp2(float x) {
#if __has_builtin(__builtin_amdgcn_exp2f)
    return __builtin_amdgcn_exp2f(x);
#else
    float r;
    asm("v_exp_f32 %0, %1" : "=v"(r) : "v"(x));
    return r;
#endif
}
__device__ __forceinline__ float nrcp(float x) {
#if __has_builtin(__builtin_amdgcn_rcpf)
    return __builtin_amdgcn_rcpf(x);
#else
    float r;
    asm("v_rcp_f32 %0, %1" : "=v"(r) : "v"(x));
    return r;
#endif
}

// tanh(x) = 1 - 2/(2^(2*log2e*x)+1). 5 VALU ops (mul,exp,add,rcp,fma).
__device__ __forceinline__ float fast_tanh(float x) {
    const float c = 2.8853900817779268f;   // 2*log2(e)
    float e = nexp2(x * c);
    float r = nrcp(e + 1.0f);
    return fmaf(-2.0f, r, 1.0f);
}

// OCCUPANCY SPLIT, attempt 3 (R7). 4 waves/block = 2 pairs; wave w = 2*hh+g:
// g = w&1 (particle group of 16), hh = w>>1 (hidden half). Each wave computes
// hidden units [64hh,64hh+64): GEMM1 = 4 MFMA, 16 tanh, GEMM2 partial over
// kt in {2hh,2hh+1}; partials combine through Zlds. Grid 1024 -> 4096 waves
// = 4/SIMD (R3 was 2048 = 2/SIMD, ~50% latency-stalled).
//
// Why R4/R6 spilled, and the fixes here:
//  - R6: X/V/nc/bxreg live across the loop but defined under divergent
//    if(hh==0) -> compiler demoted them to scratch (116 MB WRITE_SIZE).
//    FIX: ALL waves hold X/V/noise and run the update uniformly (store gated).
//  - R4: duplicate-state variant needed ~140 VGPR vs the 128 cap -> spills.
//    FIX: Stat/W1s (32 VGPR) moved to a 512 B LDS table. Threads 0-127 evolve
//    it in place once per step (Stat += dt*W1s; 1 fma + 1 ds_write, waves 0-1
//    only -> wave-uniform branch). Readers fetch 4 broadcast ds_read_b128 per
//    step; this also deletes the per-step 16-fma C-init. Peak pressure ~110.
//
// StatLds layout: flat index f = 64hh+16mt+4q+r == the hidden-unit index h,
// so updater thread tid<128 owns hidden unit h = tid. Reader frag mt at
// &StatLds[64hh+16mt+4q] (16B aligned, same addr across the 16 lanes of a
// (hh,q) group -> LDS broadcast, conflict-free). Writes sit between sync1 and
// sync2; reads at loop top (after sync2) -> race-free with the existing syncs.
__global__ __launch_bounds__(BLOCK, 4)
void fused_sde_mfma(const float* __restrict__ obs,
                    const float* __restrict__ x0,
                    const float* __restrict__ v0,
                    const float* __restrict__ noise,
                    const float* __restrict__ gW1,
                    const float* __restrict__ gb1,
                    const float* __restrict__ gW2,
                    const float* __restrict__ gb2,
                    const float* __restrict__ gtheta,
                    const int* __restrict__ gobs_idx,
                    const int* __restrict__ gctrl,
                    float* __restrict__ outX,
                    float* __restrict__ outV)
{
    // Zlds[wave][particle][dim], pitch 36 floats (144 B) -> <=2-way aliasing.
    __shared__ __align__(16) float Zlds[4][16][36];
    __shared__ __align__(16) float StatLds[128];   // evolving GEMM1 C-init

    const int tid  = threadIdx.x;
    const int w    = tid >> 6;
    const int g    = w & 1;        // particle group within block
    const int hh   = w >> 1;       // hidden half
    const int lane = tid & 63;
    const int p    = lane & 15;
    const int q    = lane >> 4;
    const int part = blockIdx.x * 32 + g * 16 + p;

    const float theta = gtheta[0];
    const float tfeat = (float)gobs_idx[0];
    const float cr    = (float)gctrl[0];
    const float dt      = 1.0f / (float)MS;
    const float sqrt_dt = sqrtf(dt);
    const float ax  = 1.0f - dt * theta;
    const float bcr = dt * cr;
    const float kv  = dt * (0.5f - cr);

    // ---- GEMM1 A-fragments: W1 X-block, this wave's hidden half ----
    bfrag A1[4];
    #pragma unroll
    for (int mt = 0; mt < 4; ++mt) {
        const int h = 64 * hh + 16 * mt + p;
        bfrag a;
        #pragma unroll
        for (int j = 0; j < 8; ++j)
            a[j] = (short)f2bf(gW1[(8 * q + j) * 128 + h]);
        A1[mt] = a;
    }

    // ---- GEMM2 B-fragments: W2 rows kappa-permuted, this wave's kt pair ----
    bfrag B2[2][2];
    #pragma unroll
    for (int nt = 0; nt < 2; ++nt) {
        #pragma unroll
        for (int ktl = 0; ktl < 2; ++ktl) {
            const int kt = 2 * hh + ktl;
            bfrag b;
            #pragma unroll
            for (int j = 0; j < 8; ++j) {
                const int h = 32 * kt + 16 * (j >> 2) + 4 * q + (j & 3);  // kappa
                b[j] = (short)f2bf(gW2[h * 32 + 16 * nt + p]);
            }
            B2[nt][ktl] = b;
        }
    }

    // ---- StatLds init: thread t<128 owns hidden unit h=t ----
    // Stat(0)[h] = b1 + Y.W1y + t*W1t ; evolves by += dt*W1s each step.
    float statreg = 0.0f, w1sreg = 0.0f;
    if (tid < 128) {
        const int h = tid;
        float acc = gb1[h];
        #pragma unroll
        for (int j = 0; j < 8; ++j)
            acc = fmaf(obs[j], gW1[(32 + j) * 128 + h], acc);
        acc = fmaf(tfeat, gW1[41 * 128 + h], acc);
        statreg = acc;
        w1sreg  = gW1[40 * 128 + h];
        StatLds[tid] = statreg;
    }

    // GEMM2 C-init: b2 carried by hh==0 waves only (partials sum via Zlds).
    const float bz0 = (hh == 0) ? gb2[p]      : 0.0f;
    const float bz1 = (hh == 0) ? gb2[16 + p] : 0.0f;

    // ---- per-lane state: ALL waves hold X/V/noise (uniform control flow) ----
    float X[8];
    {
        const float4* xp = (const float4*)(x0 + (size_t)part * 32 + 8 * q);
        float4 a = xp[0], b = xp[1];
        X[0] = a.x; X[1] = a.y; X[2] = a.z; X[3] = a.w;
        X[4] = b.x; X[5] = b.y; X[6] = b.z; X[7] = b.w;
    }
    float V = v0[part];

    const float* nbase = noise + (size_t)part * 32 + 8 * q;
    float4 nc0 = ((const float4*)nbase)[0];
    float4 nc1 = ((const float4*)nbase)[1];

    float* zbase = &Zlds[w][0][0];
    const float* zrow0 = &Zlds[g][p][0];       // hh=0 partial
    const float* zrow1 = &Zlds[2 + g][p][0];   // hh=1 partial
    const float* statbase = &StatLds[64 * hh + 4 * q];

    __syncthreads();   // StatLds(0) visible

    #pragma unroll 1
    for (int m = 0; m < MS; ++m) {
        // noise prefetch for NEXT step — hides under the GEMM phase
        const int mn = (m + 1 < MS) ? m + 1 : m;
        const float* np = nbase + (size_t)mn * ((size_t)NPART * 32);
        float4 nn0 = ((const float4*)np)[0];
        float4 nn1 = ((const float4*)np)[1];

        // B fragment: X -> packed bf16
        int4 bxw = make_int4((int)pk2(X[0], X[1]), (int)pk2(X[2], X[3]),
                             (int)pk2(X[4], X[5]), (int)pk2(X[6], X[7]));
        bfrag BX = __builtin_bit_cast(bfrag, bxw);

        // ---- GEMM1 C-init from LDS (4 broadcast ds_read_b128) ----
        ffrag Statc[4];
        #pragma unroll
        for (int mt = 0; mt < 4; ++mt)
            Statc[mt] = *(const ffrag*)(statbase + 16 * mt);

        // ---- GEMM1: 4 independent MFMAs on this wave's hidden half ----
        ffrag C[4];
        #pragma unroll
        for (int mt = 0; mt < 4; ++mt)
            C[mt] = __builtin_amdgcn_mfma_f32_16x16x32_bf16(A1[mt], BX, Statc[mt], 0, 0, 0);

        // ---- tanh + pack: C-regs become GEMM2 A-fragments directly ----
        uint2 Hpk[4];
        #pragma unroll
        for (int mt = 0; mt < 4; ++mt) {
            const unsigned u0 = pk2(fast_tanh(C[mt][0]), fast_tanh(C[mt][1]));
            const unsigned u1 = pk2(fast_tanh(C[mt][2]), fast_tanh(C[mt][3]));
            Hpk[mt] = make_uint2(u0, u1);
        }

        // ---- GEMM2 partial: this wave's kt pair ----
        ffrag D0 = ffrag{bz0, bz0, bz0, bz0};
        ffrag D1 = ffrag{bz1, bz1, bz1, bz1};
        #pragma unroll
        for (int ktl = 0; ktl < 2; ++ktl) {
            int4 aw = make_int4((int)Hpk[2 * ktl].x, (int)Hpk[2 * ktl].y,
                                (int)Hpk[2 * ktl + 1].x, (int)Hpk[2 * ktl + 1].y);
            bfrag A = __builtin_bit_cast(bfrag, aw);
            D0 = __builtin_amdgcn_mfma_f32_16x16x32_bf16(A, B2[0][ktl], D0, 0, 0, 0);
            D1 = __builtin_amdgcn_mfma_f32_16x16x32_bf16(A, B2[1][ktl], D1, 0, 0, 0);
        }

        // ---- scatter partials to [particle][dim] ----
        #pragma unroll
        for (int r = 0; r < 4; ++r) {
            float* zr = zbase + (4 * q + r) * 36;
            zr[p]      = D0[r];
            zr[16 + p] = D1[r];
        }

        __syncthreads();   // sync1: partials visible

        // evolve StatLds to step m+1 (waves 0-1; wave-uniform branch;
        // readers touch StatLds only before sync1 / after sync2 -> race-free)
        if (tid < 128) {
            statreg = fmaf(dt, w1sreg, statreg);
            StatLds[tid] = statreg;
        }

        // ---- combine partials; update (ALL waves, uniform) ----
        float4 a0 = *(const float4*)&zrow0[8 * q];
        float4 a1 = *(const float4*)&zrow0[8 * q + 4];
        float4 b0 = *(const float4*)&zrow1[8 * q];
        float4 b1 = *(const float4*)&zrow1[8 * q + 4];
        float Z[8] = {a0.x + b0.x, a0.y + b0.y, a0.z + b0.z, a0.w + b0.w,
                      a1.x + b1.x, a1.y + b1.y, a1.z + b1.z, a1.w + b1.w};
        float Nn[8] = {nc0.x, nc0.y, nc0.z, nc0.w, nc1.x, nc1.y, nc1.z, nc1.w};

        // V: (0.5-cr)*dt*sum(Z^2) + sqrt_dt*sum(Z*n)
        float s2 = 0.0f, sn = 0.0f;
        #pragma unroll
        for (int j = 0; j < 8; ++j) {
            s2 = fmaf(Z[j], Z[j], s2);
            sn = fmaf(Z[j], Nn[j], sn);
        }
        s2 += __shfl_xor(s2, 16); s2 += __shfl_xor(s2, 32);
        sn += __shfl_xor(sn, 16); sn += __shfl_xor(sn, 32);
        V = fmaf(kv, s2, fmaf(sqrt_dt, sn, V));

        // X = ax*X - bcr*Z + sqrt_dt*n
        #pragma unroll
        for (int j = 0; j < 8; ++j) {
            float t = fmaf(-bcr, Z[j], sqrt_dt * Nn[j]);
            X[j] = fmaf(ax, X[j], t);
        }

        nc0 = nn0; nc1 = nn1;

        __syncthreads();   // sync2: Zlds WAR + StatLds(m+1) visible
    }

    if (hh == 0) {
        float4* xout = (float4*)(outX + (size_t)part * 32 + 8 * q);
        xout[0] = make_float4(X[0], X[1], X[2], X[3]);
        xout[1] = make_float4(X[4], X[5], X[6], X[7]);
        if (q == 0) outV[part] = V;
    }
}

extern "C" void kernel_launch(void* const* d_in, const int* in_sizes, int n_in,
                              void* d_out, int out_size, void* d_ws, size_t ws_size,
                              hipStream_t stream) {
    const float* obs   = (const float*)d_in[0];
    const float* x0    = (const float*)d_in[1];
    const float* v0    = (const float*)d_in[2];
    const float* noise = (const float*)d_in[3];
    const float* W1    = (const float*)d_in[4];
    const float* b1    = (const float*)d_in[5];
    const float* W2    = (const float*)d_in[6];
    const float* b2    = (const float*)d_in[7];
    const float* th    = (const float*)d_in[8];
    const int*   oi    = (const int*)d_in[9];
    const int*   cr    = (const int*)d_in[10];

    float* outX = (float*)d_out;
    float* outV = outX + (size_t)NPART * 32;

    dim3 grid(NPART / 32);   // 1024 blocks x 4 waves; wave pair splits hidden
    fused_sde_mfma<<<grid, BLOCK, 0, stream>>>(obs, x0, v0, noise, W1, b1, W2, b2,
                                               th, oi, cr, outX, outV);
}